// Round 1
// baseline (5451.159 us; speedup 1.0000x reference)
//
#include <hip/hip_runtime.h>

// Hamiltonian GNN: forward + reverse-mode grad wrt state, out = state - DT*dH.
// fp32 baseline. Only nonlinearities are ReLU (masks saved as bytes) and the
// two encoder LayerNorms (save xhat=eh0/nh0 + rstd). Processor is linear ->
// backward needs no other activations.

#define E_ROWS 16384
#define N_ROWS 4096
#define LDIM   512
#define DT_F   0.01f

typedef unsigned char u8;

// ---------------------------------------------------------------------------
// Generic 512-K / 512-N fp32 GEMM: C[M,512] = epilogue(A[M,512] @ op(B))
// op(B) = B [512,512] row-major (TRANSB=0) or B^T (TRANSB=1, i.e. C=A@B^T).
// Epilogue order: acc (+G1[s]+G2[r]) (+Cin) (+bias) (relu+mask | *mask) -> C.
// BM=BN=64, BK=16, 256 threads, 4x4 per thread, float4 paths.
// ---------------------------------------------------------------------------
template<bool TRANSB, bool ADD_C, bool GATHER2, bool BIAS, bool RELU_MASK, bool APPLY_MASK>
__global__ __launch_bounds__(256)
void gemm512(const float* __restrict__ A, const float* __restrict__ B,
             float* __restrict__ C, const float* __restrict__ Cin,
             const float* __restrict__ bias,
             const float* __restrict__ G1v, const float* __restrict__ G2v,
             const int* __restrict__ sidx, const int* __restrict__ ridx,
             u8* __restrict__ mask)
{
    __shared__ float As[16][64];
    __shared__ float Bs[16][64];
    const int tid = threadIdx.x;
    const int tx = tid & 15, ty = tid >> 4;
    const int rowBase = blockIdx.y << 6;
    const int colBase = blockIdx.x << 6;

    const int lrow = tid >> 2;        // 0..63
    const int lk   = (tid & 3) << 2;  // 0,4,8,12

    float acc[4][4] = {{0.f}};

    for (int kb = 0; kb < 512; kb += 16) {
        // A tile: 64 rows x 16 k, transposed into As[k][row]
        float4 av = *reinterpret_cast<const float4*>(&A[(size_t)(rowBase + lrow) * 512 + kb + lk]);
        As[lk + 0][lrow] = av.x; As[lk + 1][lrow] = av.y;
        As[lk + 2][lrow] = av.z; As[lk + 3][lrow] = av.w;
        if (TRANSB) {
            // Bs[k][n] = B[colBase+n][kb+k]
            float4 bv = *reinterpret_cast<const float4*>(&B[(size_t)(colBase + lrow) * 512 + kb + lk]);
            Bs[lk + 0][lrow] = bv.x; Bs[lk + 1][lrow] = bv.y;
            Bs[lk + 2][lrow] = bv.z; Bs[lk + 3][lrow] = bv.w;
        } else {
            const int bk = tid >> 4, bc = (tid & 15) << 2;
            float4 bv = *reinterpret_cast<const float4*>(&B[(size_t)(kb + bk) * 512 + colBase + bc]);
            *reinterpret_cast<float4*>(&Bs[bk][bc]) = bv;
        }
        __syncthreads();
#pragma unroll
        for (int k = 0; k < 16; ++k) {
            const float4 a = *reinterpret_cast<const float4*>(&As[k][ty << 2]);
            const float4 b = *reinterpret_cast<const float4*>(&Bs[k][tx << 2]);
            acc[0][0] = fmaf(a.x, b.x, acc[0][0]); acc[0][1] = fmaf(a.x, b.y, acc[0][1]);
            acc[0][2] = fmaf(a.x, b.z, acc[0][2]); acc[0][3] = fmaf(a.x, b.w, acc[0][3]);
            acc[1][0] = fmaf(a.y, b.x, acc[1][0]); acc[1][1] = fmaf(a.y, b.y, acc[1][1]);
            acc[1][2] = fmaf(a.y, b.z, acc[1][2]); acc[1][3] = fmaf(a.y, b.w, acc[1][3]);
            acc[2][0] = fmaf(a.z, b.x, acc[2][0]); acc[2][1] = fmaf(a.z, b.y, acc[2][1]);
            acc[2][2] = fmaf(a.z, b.z, acc[2][2]); acc[2][3] = fmaf(a.z, b.w, acc[2][3]);
            acc[3][0] = fmaf(a.w, b.x, acc[3][0]); acc[3][1] = fmaf(a.w, b.y, acc[3][1]);
            acc[3][2] = fmaf(a.w, b.z, acc[3][2]); acc[3][3] = fmaf(a.w, b.w, acc[3][3]);
        }
        __syncthreads();
    }

    const int row0 = rowBase + (ty << 2);
    const int col0 = colBase + (tx << 2);
    float4 bv4 = make_float4(0.f, 0.f, 0.f, 0.f);
    if (BIAS) bv4 = *reinterpret_cast<const float4*>(&bias[col0]);
#pragma unroll
    for (int i = 0; i < 4; ++i) {
        const int row = row0 + i;
        const size_t o = (size_t)row * 512 + col0;
        float4 v = make_float4(acc[i][0], acc[i][1], acc[i][2], acc[i][3]);
        if (GATHER2) {
            const int s = sidx[row], r = ridx[row];
            const float4 g1 = *reinterpret_cast<const float4*>(&G1v[(size_t)s * 512 + col0]);
            const float4 g2 = *reinterpret_cast<const float4*>(&G2v[(size_t)r * 512 + col0]);
            v.x += g1.x + g2.x; v.y += g1.y + g2.y; v.z += g1.z + g2.z; v.w += g1.w + g2.w;
        }
        if (ADD_C) {
            const float4 c = *reinterpret_cast<const float4*>(&Cin[o]);
            v.x += c.x; v.y += c.y; v.z += c.z; v.w += c.w;
        }
        if (BIAS) { v.x += bv4.x; v.y += bv4.y; v.z += bv4.z; v.w += bv4.w; }
        if (RELU_MASK) {
            uchar4 m;
            m.x = v.x > 0.f; m.y = v.y > 0.f; m.z = v.z > 0.f; m.w = v.w > 0.f;
            v.x = m.x ? v.x : 0.f; v.y = m.y ? v.y : 0.f;
            v.z = m.z ? v.z : 0.f; v.w = m.w ? v.w : 0.f;
            *reinterpret_cast<uchar4*>(&mask[o]) = m;
        }
        if (APPLY_MASK) {
            const uchar4 m = *reinterpret_cast<const uchar4*>(&mask[o]);
            if (!m.x) v.x = 0.f; if (!m.y) v.y = 0.f;
            if (!m.z) v.z = 0.f; if (!m.w) v.w = 0.f;
        }
        *reinterpret_cast<float4*>(&C[o]) = v;
    }
}

// ---------------------------------------------------------------------------
// Encoder layer-1: h1[row][c] = relu(x[row]*W1[c] + b1[c]), store mask.
// grid = rows*128/256 (one float4 per thread).
// ---------------------------------------------------------------------------
__global__ void enc_h1_kernel(const float* __restrict__ x, const float* __restrict__ W1,
                              const float* __restrict__ b1, float* __restrict__ h1,
                              u8* __restrict__ mask)
{
    const int idx = blockIdx.x * 256 + threadIdx.x;
    const int row = idx >> 7;
    const int c = (idx & 127) << 2;
    const float xv = x[row];
    const float4 w = *reinterpret_cast<const float4*>(&W1[c]);
    const float4 b = *reinterpret_cast<const float4*>(&b1[c]);
    float4 v;
    v.x = fmaf(xv, w.x, b.x); v.y = fmaf(xv, w.y, b.y);
    v.z = fmaf(xv, w.z, b.z); v.w = fmaf(xv, w.w, b.w);
    uchar4 m;
    m.x = v.x > 0.f; m.y = v.y > 0.f; m.z = v.z > 0.f; m.w = v.w > 0.f;
    v.x = m.x ? v.x : 0.f; v.y = m.y ? v.y : 0.f;
    v.z = m.z ? v.z : 0.f; v.w = m.w ? v.w : 0.f;
    const size_t o = (size_t)row * 512 + c;
    *reinterpret_cast<float4*>(&h1[o]) = v;
    *reinterpret_cast<uchar4*>(&mask[o]) = m;
}

// LayerNorm forward, in-place on x, saves xhat (== output) and rstd. 1 block/row.
__global__ void ln_fwd_kernel(float* __restrict__ x, float* __restrict__ xhat_save,
                              float* __restrict__ rstd_save)
{
    const int row = blockIdx.x, tid = threadIdx.x;
    float* p = x + (size_t)row * 512;
    const float a = p[tid], b = p[tid + 256];
    __shared__ float s1[256], s2[256];
    s1[tid] = a + b; s2[tid] = a * a + b * b;
    __syncthreads();
    for (int d = 128; d > 0; d >>= 1) {
        if (tid < d) { s1[tid] += s1[tid + d]; s2[tid] += s2[tid + d]; }
        __syncthreads();
    }
    const float mean = s1[0] * (1.f / 512.f);
    const float var = s2[0] * (1.f / 512.f) - mean * mean;
    const float r = rsqrtf(var + 1e-6f);
    const float ya = (a - mean) * r, yb = (b - mean) * r;
    p[tid] = ya; p[tid + 256] = yb;
    xhat_save[(size_t)row * 512 + tid] = ya;
    xhat_save[(size_t)row * 512 + tid + 256] = yb;
    if (tid == 0) rstd_save[row] = r;
}

// LayerNorm backward, in-place on d: dx = r*(dy - mean(dy) - xhat*mean(dy*xhat)).
__global__ void ln_bwd_kernel(float* __restrict__ d, const float* __restrict__ xhat,
                              const float* __restrict__ rstd)
{
    const int row = blockIdx.x, tid = threadIdx.x;
    float* p = d + (size_t)row * 512;
    const float* xh = xhat + (size_t)row * 512;
    const float da = p[tid], db = p[tid + 256];
    const float xa = xh[tid], xb = xh[tid + 256];
    __shared__ float s1[256], s2[256];
    s1[tid] = da + db; s2[tid] = da * xa + db * xb;
    __syncthreads();
    for (int dd = 128; dd > 0; dd >>= 1) {
        if (tid < dd) { s1[tid] += s1[tid + dd]; s2[tid] += s2[tid + dd]; }
        __syncthreads();
    }
    const float m1 = s1[0] * (1.f / 512.f);
    const float m2 = s2[0] * (1.f / 512.f);
    const float r = rstd[row];
    p[tid] = r * (da - m1 - xa * m2);
    p[tid + 256] = r * (db - m1 - xb * m2);
}

// dst[idx[row]][col] += src[row][col] (atomic). grid = rows*512/256.
__global__ void scatter_add_kernel(const float* __restrict__ src, const int* __restrict__ idx,
                                   float* __restrict__ dst)
{
    const int t = blockIdx.x * 256 + threadIdx.x;
    const int row = t >> 9, col = t & 511;
    atomicAdd(dst + (size_t)idx[row] * 512 + col, src[t]);
}

// dst[row][c..] += src[idx[row]][c..] (float4). grid = rows*128/256.
__global__ void gather_add_kernel(float* __restrict__ dst, const float* __restrict__ src,
                                  const int* __restrict__ idx)
{
    const int t = blockIdx.x * 256 + threadIdx.x;
    const int row = t >> 7;
    const int c = (t & 127) << 2;
    const size_t o = (size_t)row * 512 + c;
    float4 a = *reinterpret_cast<const float4*>(&dst[o]);
    const float4 g = *reinterpret_cast<const float4*>(&src[(size_t)idx[row] * 512 + c]);
    a.x += g.x; a.y += g.y; a.z += g.z; a.w += g.w;
    *reinterpret_cast<float4*>(&dst[o]) = a;
}

// Decoder backward layer-2: dh1[row][c] = mask ? W2[c] : 0 (ddec = 1 per edge).
__global__ void dec_dh1_kernel(const u8* __restrict__ mask, const float* __restrict__ W2,
                               float* __restrict__ dh1)
{
    const int t = blockIdx.x * 256 + threadIdx.x;
    const int row = t >> 7;
    const int c = (t & 127) << 2;
    const size_t o = (size_t)row * 512 + c;
    const uchar4 m = *reinterpret_cast<const uchar4*>(&mask[o]);
    const float4 w = *reinterpret_cast<const float4*>(&W2[c]);
    float4 v;
    v.x = m.x ? w.x : 0.f; v.y = m.y ? w.y : 0.f;
    v.z = m.z ? w.z : 0.f; v.w = m.w ? w.w : 0.f;
    *reinterpret_cast<float4*>(&dh1[o]) = v;
}

// out[row] = xin[row] - DT * dot(dh1[row,:], w[:]). 1 block/row.
__global__ void rowdot_out_kernel(const float* __restrict__ dh1, const float* __restrict__ w,
                                  const float* __restrict__ xin, float* __restrict__ out)
{
    const int row = blockIdx.x, tid = threadIdx.x;
    const float* p = dh1 + (size_t)row * 512;
    float s = p[tid] * w[tid] + p[tid + 256] * w[tid + 256];
    __shared__ float sh[256];
    sh[tid] = s;
    __syncthreads();
    for (int d = 128; d > 0; d >>= 1) {
        if (tid < d) sh[tid] += sh[tid + d];
        __syncthreads();
    }
    if (tid == 0) out[row] = xin[row] - DT_F * sh[0];
}

// ---------------------------------------------------------------------------
extern "C" void kernel_launch(void* const* d_in, const int* in_sizes, int n_in,
                              void* d_out, int out_size, void* d_ws, size_t ws_size,
                              hipStream_t stream)
{
    (void)in_sizes; (void)n_in; (void)out_size; (void)ws_size;
    const float* state     = (const float*)d_in[0];
    const int*   senders   = (const int*)d_in[1];
    const int*   receivers = (const int*)d_in[2];
    const float* enc_e_W1 = (const float*)d_in[3];
    const float* enc_e_b1 = (const float*)d_in[4];
    const float* enc_e_W2 = (const float*)d_in[5];
    const float* enc_e_b2 = (const float*)d_in[6];
    const float* enc_n_W1 = (const float*)d_in[7];
    const float* enc_n_b1 = (const float*)d_in[8];
    const float* enc_n_W2 = (const float*)d_in[9];
    const float* enc_n_b2 = (const float*)d_in[10];
    const float* pe_W1 = (const float*)d_in[11];
    const float* pe_b1 = (const float*)d_in[12];
    const float* pe_W2 = (const float*)d_in[13];
    const float* pe_b2 = (const float*)d_in[14];
    const float* pn_W1 = (const float*)d_in[15];
    const float* pn_b1 = (const float*)d_in[16];
    const float* pn_W2 = (const float*)d_in[17];
    const float* pn_b2 = (const float*)d_in[18];
    const float* de_W1 = (const float*)d_in[19];
    const float* de_b1 = (const float*)d_in[20];
    const float* de_W2 = (const float*)d_in[21];
    float* out = (float*)d_out;

    const size_t EL = (size_t)E_ROWS * 512, NL = (size_t)N_ROWS * 512;
    const size_t LL = 512 * 512;
    char* w = (char*)d_ws;
    size_t off = 0;
    auto carve = [&](size_t bytes) -> char* {
        char* p = w + off;
        off += (bytes + 255) & ~(size_t)255;
        return p;
    };
    float* eh0    = (float*)carve(EL * 4);   // LN xhat (edges)
    float* nh0    = (float*)carve(NL * 4);   // LN xhat (nodes)
    float* rstd_e = (float*)carve(E_ROWS * 4);
    float* rstd_n = (float*)carve(N_ROWS * 4);
    u8* mask_enc_e = (u8*)carve(EL);
    u8* mask_enc_n = (u8*)carve(NL);
    u8* mask_pe    = (u8*)carve(5 * EL);
    u8* mask_pn    = (u8*)carve(5 * NL);
    u8* mask_dec   = (u8*)carve(EL);
    float* eh  = (float*)carve(EL * 4);      // fwd: eh      | bwd: d_eh
    float* nh  = (float*)carve(NL * 4);      // fwd: nh      | bwd: d_nh
    float* h1e = (float*)carve(EL * 4);      // edge hidden / dh1_e / dec hidden
    float* h1n = (float*)carve(NL * 4);      // node hidden / dh1_n
    float* G1  = (float*)carve(NL * 4);      // fwd: nh@W1b  | bwd: d_agg
    float* G2  = (float*)carve(NL * 4);      // fwd: nh@W1c  | bwd: Ssum
    float* agg = (float*)carve(NL * 4);      // fwd: agg     | bwd: Rsum

    const dim3 blk(256);
    const dim3 gE(8, E_ROWS / 64), gN(8, N_ROWS / 64);
    const float* np = nullptr;
    const int* ip = nullptr;
    u8* up = nullptr;

    // ================= FORWARD =================
    // encoders: h1 = relu(x*W1+b1); pre = h1@W2+b2; LN -> (eh, eh0, rstd)
    enc_h1_kernel<<<E_ROWS * 128 / 256, blk, 0, stream>>>(state, enc_e_W1, enc_e_b1, h1e, mask_enc_e);
    gemm512<false,false,false,true,false,false><<<gE, blk, 0, stream>>>(h1e, enc_e_W2, eh, np, enc_e_b2, np, np, ip, ip, up);
    ln_fwd_kernel<<<E_ROWS, blk, 0, stream>>>(eh, eh0, rstd_e);
    enc_h1_kernel<<<N_ROWS * 128 / 256, blk, 0, stream>>>(state + E_ROWS, enc_n_W1, enc_n_b1, h1n, mask_enc_n);
    gemm512<false,false,false,true,false,false><<<gN, blk, 0, stream>>>(h1n, enc_n_W2, nh, np, enc_n_b2, np, np, ip, ip, up);
    ln_fwd_kernel<<<N_ROWS, blk, 0, stream>>>(nh, nh0, rstd_n);

    // processor: 5 message-passing steps
    for (int k = 0; k < 5; ++k) {
        // G1 = nh@W1b, G2 = nh@W1c  (split of the [E,3L]@[3L,L] concat GEMM)
        gemm512<false,false,false,false,false,false><<<gN, blk, 0, stream>>>(nh, pe_W1 + LL, G1, np, np, np, np, ip, ip, up);
        gemm512<false,false,false,false,false,false><<<gN, blk, 0, stream>>>(nh, pe_W1 + 2 * LL, G2, np, np, np, np, ip, ip, up);
        // h1e = relu(eh@W1a + G1[s] + G2[r] + b1), save mask
        gemm512<false,false,true,true,true,false><<<gE, blk, 0, stream>>>(eh, pe_W1, h1e, np, pe_b1, G1, G2, senders, receivers, mask_pe + (size_t)k * EL);
        // eh += h1e@W2 + b2
        gemm512<false,true,false,true,false,false><<<gE, blk, 0, stream>>>(h1e, pe_W2, eh, eh, pe_b2, np, np, ip, ip, up);
        // agg = segment_sum(eh, receivers)
        hipMemsetAsync(agg, 0, NL * 4, stream);
        scatter_add_kernel<<<E_ROWS * 512 / 256, blk, 0, stream>>>(eh, receivers, agg);
        // h1n = relu(nh@W1na + agg@W1nb + b1), save mask
        gemm512<false,false,false,false,false,false><<<gN, blk, 0, stream>>>(nh, pn_W1, h1n, np, np, np, np, ip, ip, up);
        gemm512<false,true,false,true,true,false><<<gN, blk, 0, stream>>>(agg, pn_W1 + LL, h1n, h1n, pn_b1, np, np, ip, ip, mask_pn + (size_t)k * NL);
        // nh += h1n@W2 + b2
        gemm512<false,true,false,true,false,false><<<gN, blk, 0, stream>>>(h1n, pn_W2, nh, nh, pn_b2, np, np, ip, ip, up);
    }

    // decoder layer-1 (only the mask matters; H value itself not needed)
    gemm512<false,false,false,true,true,false><<<gE, blk, 0, stream>>>(eh, de_W1, h1e, np, de_b1, np, np, ip, ip, mask_dec);

    // ================= BACKWARD =================
    // ddec = 1 -> dh1_d = mask * W2 ; d_eh = dh1_d @ W1^T ; d_nh = 0
    dec_dh1_kernel<<<E_ROWS * 128 / 256, blk, 0, stream>>>(mask_dec, de_W2, h1e);
    gemm512<true,false,false,false,false,false><<<gE, blk, 0, stream>>>(h1e, de_W1, eh, np, np, np, np, ip, ip, up);
    hipMemsetAsync(nh, 0, NL * 4, stream);

    for (int k = 4; k >= 0; --k) {
        // node MLP backward: dh1_n = (d_nh @ W2^T) * mask
        gemm512<true,false,false,false,false,true><<<gN, blk, 0, stream>>>(nh, pn_W2, h1n, np, np, np, np, ip, ip, mask_pn + (size_t)k * NL);
        // d_nh += dh1_n @ W1na^T ; d_agg = dh1_n @ W1nb^T
        gemm512<true,true,false,false,false,false><<<gN, blk, 0, stream>>>(h1n, pn_W1, nh, nh, np, np, np, ip, ip, up);
        gemm512<true,false,false,false,false,false><<<gN, blk, 0, stream>>>(h1n, pn_W1 + LL, G1, np, np, np, np, ip, ip, up);
        // d_eh += d_agg[receivers]  (segment_sum backward)
        gather_add_kernel<<<E_ROWS * 128 / 256, blk, 0, stream>>>(eh, G1, receivers);
        // edge MLP backward: dh1_e = (d_eh @ W2^T) * mask ; d_eh += dh1_e @ W1a^T
        gemm512<true,false,false,false,false,true><<<gE, blk, 0, stream>>>(eh, pe_W2, h1e, np, np, np, np, ip, ip, mask_pe + (size_t)k * EL);
        gemm512<true,true,false,false,false,false><<<gE, blk, 0, stream>>>(h1e, pe_W1, eh, eh, np, np, np, ip, ip, up);
        // d_nh += segsum(dh1_e, senders)@W1b^T + segsum(dh1_e, receivers)@W1c^T
        hipMemsetAsync(G2, 0, NL * 4, stream);
        hipMemsetAsync(agg, 0, NL * 4, stream);
        scatter_add_kernel<<<E_ROWS * 512 / 256, blk, 0, stream>>>(h1e, senders, G2);
        scatter_add_kernel<<<E_ROWS * 512 / 256, blk, 0, stream>>>(h1e, receivers, agg);
        gemm512<true,true,false,false,false,false><<<gN, blk, 0, stream>>>(G2, pe_W1 + LL, nh, nh, np, np, np, ip, ip, up);
        gemm512<true,true,false,false,false,false><<<gN, blk, 0, stream>>>(agg, pe_W1 + 2 * LL, nh, nh, np, np, np, ip, ip, up);
    }

    // encoder backward (LN bwd -> MLP bwd -> scalar grad) + final axpy
    ln_bwd_kernel<<<E_ROWS, blk, 0, stream>>>(eh, eh0, rstd_e);
    gemm512<true,false,false,false,false,true><<<gE, blk, 0, stream>>>(eh, enc_e_W2, h1e, np, np, np, np, ip, ip, mask_enc_e);
    rowdot_out_kernel<<<E_ROWS, blk, 0, stream>>>(h1e, enc_e_W1, state, out);
    ln_bwd_kernel<<<N_ROWS, blk, 0, stream>>>(nh, nh0, rstd_n);
    gemm512<true,false,false,false,false,true><<<gN, blk, 0, stream>>>(nh, enc_n_W2, h1n, np, np, np, np, ip, ip, mask_enc_n);
    rowdot_out_kernel<<<N_ROWS, blk, 0, stream>>>(h1n, enc_n_W1, state + E_ROWS, out + E_ROWS);
}

// Round 2
// 1969.809 us; speedup vs baseline: 2.7674x; 2.7674x over previous
//
#include <hip/hip_runtime.h>

// Hamiltonian GNN fwd+grad, out = state - DT*dH.
// Round 2: all GEMMs -> bf16 MFMA (16x16x32), m97-style 128^2 tile,
// global_load_lds staging. fp32 kept for residuals / LN stats / atomics.

#define E_ROWS 16384
#define N_ROWS 4096
#define DT_F   0.01f

typedef unsigned char u8;
typedef unsigned short u16;
typedef __attribute__((ext_vector_type(8))) short short8v;   // 8 bf16 = 4 VGPR
typedef __attribute__((ext_vector_type(4))) float f32x4;

__device__ __forceinline__ u16 f2b(float f) {
    union { float f; unsigned u; } v; v.f = f;
    unsigned r = v.u + 0x7FFF + ((v.u >> 16) & 1);
    return (u16)(r >> 16);
}
__device__ __forceinline__ float b2f(u16 u) {
    union { unsigned u; float f; } v; v.u = ((unsigned)u) << 16;
    return v.f;
}

// ---------------------------------------------------------------------------
// bf16 MFMA GEMM: C[M,512] = epi(A[M,512] @ Bt[512,512]^T), A/Bt bf16 row-major
// (Bt is output-major: Bt[n][k] = op(B)[k][n]). 128x128 tile, BK=32, 4 waves.
// ---------------------------------------------------------------------------
template<bool ADD_C, bool GATHER2, bool BIAS, bool RELU_MASK, bool APPLY_MASK,
         bool WF32, bool WBF16>
__global__ __launch_bounds__(256)
void bgemm(const u16* __restrict__ A, const u16* __restrict__ Bt,
           float* __restrict__ C, u16* __restrict__ Cb,
           const float* __restrict__ Cin, const float* __restrict__ bias,
           const float* __restrict__ G1v, const float* __restrict__ G2v,
           const int* __restrict__ sidx, const int* __restrict__ ridx,
           u8* __restrict__ maskw)
{
    __shared__ u16 Al[4096];   // [128][32] bf16
    __shared__ u16 Bl[4096];
    const int tid = threadIdx.x;
    const int lane = tid & 63;
    const int wv = tid >> 6;
    const int wr = wv >> 1, wc = wv & 1;
    const int rowBase = blockIdx.y << 7;
    const int colBase = blockIdx.x << 7;

    // staging: thread t -> row t>>2 (of 64-row half), k-slot (t&3)*8
    const int srow = tid >> 2;
    const int kel = (tid & 3) << 3;
    const u16* Ag = A + (size_t)(rowBase + srow) * 512 + kel;
    const u16* Bg = Bt + (size_t)(colBase + srow) * 512 + kel;
    u16* Ad = Al + (wv << 9);   // wave-uniform dest base (linear, lane*16B)
    u16* Bd = Bl + (wv << 9);

    f32x4 acc[4][4];
#pragma unroll
    for (int i = 0; i < 4; ++i)
#pragma unroll
        for (int j = 0; j < 4; ++j)
            acc[i][j] = (f32x4){0.f, 0.f, 0.f, 0.f};

    const int arow = (wr << 6) + (lane & 15);
    const int brow = (wc << 6) + (lane & 15);
    const int koff = (lane >> 4) << 3;

    for (int kb = 0; kb < 512; kb += 32) {
        __builtin_amdgcn_global_load_lds((const __attribute__((address_space(1))) void*)(Ag + kb),
                                         (__attribute__((address_space(3))) void*)Ad, 16, 0, 0);
        __builtin_amdgcn_global_load_lds((const __attribute__((address_space(1))) void*)(Ag + kb + (size_t)64 * 512),
                                         (__attribute__((address_space(3))) void*)(Ad + 2048), 16, 0, 0);
        __builtin_amdgcn_global_load_lds((const __attribute__((address_space(1))) void*)(Bg + kb),
                                         (__attribute__((address_space(3))) void*)Bd, 16, 0, 0);
        __builtin_amdgcn_global_load_lds((const __attribute__((address_space(1))) void*)(Bg + kb + (size_t)64 * 512),
                                         (__attribute__((address_space(3))) void*)(Bd + 2048), 16, 0, 0);
        __syncthreads();
        short8v af[4], bf[4];
#pragma unroll
        for (int i = 0; i < 4; ++i)
            af[i] = *(const short8v*)&Al[((arow + (i << 4)) << 5) + koff];
#pragma unroll
        for (int j = 0; j < 4; ++j)
            bf[j] = *(const short8v*)&Bl[((brow + (j << 4)) << 5) + koff];
#pragma unroll
        for (int i = 0; i < 4; ++i)
#pragma unroll
            for (int j = 0; j < 4; ++j)
                acc[i][j] = __builtin_amdgcn_mfma_f32_16x16x32_bf16(af[i], bf[j], acc[i][j], 0, 0, 0);
        __syncthreads();
    }

    // epilogue: D[row = (lane>>4)*4 + r, col = lane&15] per 16x16 frag
    const int colB = colBase + (wc << 6) + (lane & 15);
    const int rowB = rowBase + (wr << 6) + ((lane >> 4) << 2);
    float bcol[4];
    if (BIAS) {
#pragma unroll
        for (int j = 0; j < 4; ++j) bcol[j] = bias[colB + (j << 4)];
    }
#pragma unroll
    for (int i = 0; i < 4; ++i) {
#pragma unroll
        for (int r = 0; r < 4; ++r) {
            const int row = rowB + (i << 4) + r;
            int si = 0, ri = 0;
            if (GATHER2) { si = sidx[row]; ri = ridx[row]; }
#pragma unroll
            for (int j = 0; j < 4; ++j) {
                const int col = colB + (j << 4);
                float v = acc[i][j][r];
                if (GATHER2) v += G1v[(size_t)si * 512 + col] + G2v[(size_t)ri * 512 + col];
                if (ADD_C) v += Cin[(size_t)row * 512 + col];
                if (BIAS) v += bcol[j];
                const size_t o = (size_t)row * 512 + col;
                if (RELU_MASK) {
                    const u8 m = v > 0.f;
                    maskw[o] = m;
                    v = m ? v : 0.f;
                }
                if (APPLY_MASK) {
                    if (!maskw[o]) v = 0.f;
                }
                if (WF32) C[o] = v;
                if (WBF16) Cb[o] = f2b(v);
            }
        }
    }
}

// ---------------------------------------------------------------------------
// Weight convert: Wp[r][c] = bf16(W[r][c]); Wt[c][r] = bf16(W[r][c]). 512x512.
// grid (8,8), 256 thr, 64x64 LDS tile.
// ---------------------------------------------------------------------------
__global__ void wcvt_kernel(const float* __restrict__ W, u16* __restrict__ Wp,
                            u16* __restrict__ Wt)
{
    __shared__ u16 t[64][66];
    const int rb = blockIdx.y << 6, cb = blockIdx.x << 6;
    const int tr = threadIdx.x >> 4;
    const int tc = (threadIdx.x & 15) << 2;
#pragma unroll
    for (int rr = 0; rr < 4; ++rr) {
        const int r = tr + (rr << 4);
        const float4 v = *(const float4*)&W[(size_t)(rb + r) * 512 + cb + tc];
        ushort4 u; u.x = f2b(v.x); u.y = f2b(v.y); u.z = f2b(v.z); u.w = f2b(v.w);
        *(ushort4*)&Wp[(size_t)(rb + r) * 512 + cb + tc] = u;
        t[r][tc] = u.x; t[r][tc + 1] = u.y; t[r][tc + 2] = u.z; t[r][tc + 3] = u.w;
    }
    __syncthreads();
#pragma unroll
    for (int rr = 0; rr < 4; ++rr) {
        const int n = tr + (rr << 4);
        ushort4 u;
        u.x = t[tc][n]; u.y = t[tc + 1][n]; u.z = t[tc + 2][n]; u.w = t[tc + 3][n];
        *(ushort4*)&Wt[(size_t)(cb + n) * 512 + rb + tc] = u;
    }
}

// Encoder layer-1: h1 = relu(x*W1+b1) -> bf16 + mask.
__global__ void enc_h1_kernel(const float* __restrict__ x, const float* __restrict__ W1,
                              const float* __restrict__ b1, u16* __restrict__ h1b,
                              u8* __restrict__ mask)
{
    const int idx = blockIdx.x * 256 + threadIdx.x;
    const int row = idx >> 7;
    const int c = (idx & 127) << 2;
    const float xv = x[row];
    const float4 w = *(const float4*)&W1[c];
    const float4 b = *(const float4*)&b1[c];
    float4 v;
    v.x = fmaf(xv, w.x, b.x); v.y = fmaf(xv, w.y, b.y);
    v.z = fmaf(xv, w.z, b.z); v.w = fmaf(xv, w.w, b.w);
    uchar4 m;
    m.x = v.x > 0.f; m.y = v.y > 0.f; m.z = v.z > 0.f; m.w = v.w > 0.f;
    v.x = m.x ? v.x : 0.f; v.y = m.y ? v.y : 0.f;
    v.z = m.z ? v.z : 0.f; v.w = m.w ? v.w : 0.f;
    const size_t o = (size_t)row * 512 + c;
    ushort4 u; u.x = f2b(v.x); u.y = f2b(v.y); u.z = f2b(v.z); u.w = f2b(v.w);
    *(ushort4*)&h1b[o] = u;
    *(uchar4*)&mask[o] = m;
}

// LN fwd in-place fp32, save xhat bf16 (persist) + bf16 working copy + rstd.
__global__ void ln_fwd_kernel(float* __restrict__ x, u16* __restrict__ xhat_b,
                              u16* __restrict__ xb, float* __restrict__ rstd_save)
{
    const int row = blockIdx.x, tid = threadIdx.x;
    float* p = x + (size_t)row * 512;
    const float a = p[tid], b = p[tid + 256];
    __shared__ float s1[256], s2[256];
    s1[tid] = a + b; s2[tid] = a * a + b * b;
    __syncthreads();
    for (int d = 128; d > 0; d >>= 1) {
        if (tid < d) { s1[tid] += s1[tid + d]; s2[tid] += s2[tid + d]; }
        __syncthreads();
    }
    const float mean = s1[0] * (1.f / 512.f);
    const float var = s2[0] * (1.f / 512.f) - mean * mean;
    const float r = rsqrtf(var + 1e-6f);
    const float ya = (a - mean) * r, yb = (b - mean) * r;
    p[tid] = ya; p[tid + 256] = yb;
    const size_t o = (size_t)row * 512 + tid;
    xhat_b[o] = f2b(ya); xhat_b[o + 256] = f2b(yb);
    xb[o] = f2b(ya); xb[o + 256] = f2b(yb);
    if (tid == 0) rstd_save[row] = r;
}

// LN bwd in-place fp32 + bf16 copy. dx = r*(dy - mean(dy) - xhat*mean(dy*xhat)).
__global__ void ln_bwd_kernel(float* __restrict__ d, const u16* __restrict__ xhat_b,
                              const float* __restrict__ rstd, u16* __restrict__ db)
{
    const int row = blockIdx.x, tid = threadIdx.x;
    float* p = d + (size_t)row * 512;
    const u16* xh = xhat_b + (size_t)row * 512;
    const float da = p[tid], dbv = p[tid + 256];
    const float xa = b2f(xh[tid]), xbv = b2f(xh[tid + 256]);
    __shared__ float s1[256], s2[256];
    s1[tid] = da + dbv; s2[tid] = da * xa + dbv * xbv;
    __syncthreads();
    for (int dd = 128; dd > 0; dd >>= 1) {
        if (tid < dd) { s1[tid] += s1[tid + dd]; s2[tid] += s2[tid + dd]; }
        __syncthreads();
    }
    const float m1 = s1[0] * (1.f / 512.f);
    const float m2 = s2[0] * (1.f / 512.f);
    const float r = rstd[row];
    const float oa = r * (da - m1 - xa * m2);
    const float ob = r * (dbv - m1 - xbv * m2);
    p[tid] = oa; p[tid + 256] = ob;
    db[(size_t)row * 512 + tid] = f2b(oa);
    db[(size_t)row * 512 + tid + 256] = f2b(ob);
}

// scatter: dst[idx[row]][col] += src[row][col]
__global__ void scatter_add_kernel(const float* __restrict__ src, const int* __restrict__ idx,
                                   float* __restrict__ dst)
{
    const int t = blockIdx.x * 256 + threadIdx.x;
    const int row = t >> 9, col = t & 511;
    atomicAdd(dst + (size_t)idx[row] * 512 + col, src[t]);
}
__global__ void scatter_add_bf_kernel(const u16* __restrict__ src, const int* __restrict__ idx,
                                      float* __restrict__ dst)
{
    const int t = blockIdx.x * 256 + threadIdx.x;
    const int row = t >> 9, col = t & 511;
    atomicAdd(dst + (size_t)idx[row] * 512 + col, b2f(src[t]));
}

// dst[row] += src[idx[row]] ; also refresh bf16 copy.
__global__ void gather_add_kernel(float* __restrict__ dst, u16* __restrict__ dstb,
                                  const float* __restrict__ src, const int* __restrict__ idx)
{
    const int t = blockIdx.x * 256 + threadIdx.x;
    const int row = t >> 7;
    const int c = (t & 127) << 2;
    const size_t o = (size_t)row * 512 + c;
    float4 a = *(const float4*)&dst[o];
    const float4 g = *(const float4*)&src[(size_t)idx[row] * 512 + c];
    a.x += g.x; a.y += g.y; a.z += g.z; a.w += g.w;
    *(float4*)&dst[o] = a;
    ushort4 u; u.x = f2b(a.x); u.y = f2b(a.y); u.z = f2b(a.z); u.w = f2b(a.w);
    *(ushort4*)&dstb[o] = u;
}

__global__ void cvt_f2b_kernel(const float* __restrict__ src, u16* __restrict__ dst)
{
    const int t = blockIdx.x * 256 + threadIdx.x;
    const float4 v = *(const float4*)&src[(size_t)t * 4];
    ushort4 u; u.x = f2b(v.x); u.y = f2b(v.y); u.z = f2b(v.z); u.w = f2b(v.w);
    *(ushort4*)&dst[(size_t)t * 4] = u;
}

// dh1_dec = mask ? W2 : 0 (bf16)
__global__ void dec_dh1_kernel(const u8* __restrict__ mask, const float* __restrict__ W2,
                               u16* __restrict__ dh1b)
{
    const int t = blockIdx.x * 256 + threadIdx.x;
    const int row = t >> 7;
    const int c = (t & 127) << 2;
    const size_t o = (size_t)row * 512 + c;
    const uchar4 m = *(const uchar4*)&mask[o];
    const float4 w = *(const float4*)&W2[c];
    ushort4 u;
    u.x = m.x ? f2b(w.x) : 0; u.y = m.y ? f2b(w.y) : 0;
    u.z = m.z ? f2b(w.z) : 0; u.w = m.w ? f2b(w.w) : 0;
    *(ushort4*)&dh1b[o] = u;
}

// out[row] = xin[row] - DT * dot(dh1_b[row,:], w)
__global__ void rowdot_out_kernel(const u16* __restrict__ dh1b, const float* __restrict__ w,
                                  const float* __restrict__ xin, float* __restrict__ out)
{
    const int row = blockIdx.x, tid = threadIdx.x;
    const u16* p = dh1b + (size_t)row * 512;
    float s = b2f(p[tid]) * w[tid] + b2f(p[tid + 256]) * w[tid + 256];
    __shared__ float sh[256];
    sh[tid] = s;
    __syncthreads();
    for (int d = 128; d > 0; d >>= 1) {
        if (tid < d) sh[tid] += sh[tid + d];
        __syncthreads();
    }
    if (tid == 0) out[row] = xin[row] - DT_F * sh[0];
}

// ---------------------------------------------------------------------------
extern "C" void kernel_launch(void* const* d_in, const int* in_sizes, int n_in,
                              void* d_out, int out_size, void* d_ws, size_t ws_size,
                              hipStream_t stream)
{
    (void)in_sizes; (void)n_in; (void)out_size; (void)ws_size;
    const float* state     = (const float*)d_in[0];
    const int*   senders   = (const int*)d_in[1];
    const int*   receivers = (const int*)d_in[2];
    const float* enc_e_W1 = (const float*)d_in[3];
    const float* enc_e_b1 = (const float*)d_in[4];
    const float* enc_e_W2 = (const float*)d_in[5];
    const float* enc_e_b2 = (const float*)d_in[6];
    const float* enc_n_W1 = (const float*)d_in[7];
    const float* enc_n_b1 = (const float*)d_in[8];
    const float* enc_n_W2 = (const float*)d_in[9];
    const float* enc_n_b2 = (const float*)d_in[10];
    const float* pe_W1 = (const float*)d_in[11];
    const float* pe_b1 = (const float*)d_in[12];
    const float* pe_W2 = (const float*)d_in[13];
    const float* pe_b2 = (const float*)d_in[14];
    const float* pn_W1 = (const float*)d_in[15];
    const float* pn_b1 = (const float*)d_in[16];
    const float* pn_W2 = (const float*)d_in[17];
    const float* pn_b2 = (const float*)d_in[18];
    const float* de_W1 = (const float*)d_in[19];
    const float* de_b1 = (const float*)d_in[20];
    const float* de_W2 = (const float*)d_in[21];
    float* out = (float*)d_out;

    const size_t EL = (size_t)E_ROWS * 512, NL = (size_t)N_ROWS * 512;
    const size_t LL = 512 * 512;
    char* w = (char*)d_ws;
    size_t off = 0;
    auto carve = [&](size_t bytes) -> char* {
        char* p = w + off;
        off += (bytes + 255) & ~(size_t)255;
        return p;
    };
    // bf16 weights: per block i, WP[i]=plain, WT[i]=transposed
    u16* wb = (u16*)carve(20 * LL * 2);
    auto WP = [&](int i) { return wb + (size_t)(2 * i) * LL; };
    auto WT = [&](int i) { return wb + (size_t)(2 * i + 1) * LL; };
    float* eh  = (float*)carve(EL * 4);
    float* nh  = (float*)carve(NL * 4);
    float* G1  = (float*)carve(NL * 4);
    float* G2  = (float*)carve(NL * 4);
    float* agg = (float*)carve(NL * 4);
    u16* eh0b = (u16*)carve(EL * 2);
    u16* nh0b = (u16*)carve(NL * 2);
    u16* ehb  = (u16*)carve(EL * 2);
    u16* h1eb = (u16*)carve(EL * 2);
    u16* nhb  = (u16*)carve(NL * 2);
    u16* h1nb = (u16*)carve(NL * 2);
    u16* cvtb = (u16*)carve(NL * 2);
    float* rstd_e = (float*)carve(E_ROWS * 4);
    float* rstd_n = (float*)carve(N_ROWS * 4);
    u8* menc_e = (u8*)carve(EL);
    u8* menc_n = (u8*)carve(NL);
    u8* mpe    = (u8*)carve(5 * EL);
    u8* mpn    = (u8*)carve(5 * NL);
    u8* mdec   = (u8*)carve(EL);

    const dim3 blk(256);
    const dim3 gE(4, E_ROWS / 128), gN(4, N_ROWS / 128);
    const dim3 gW(8, 8);
    const float* fp = nullptr;
    u16* up = nullptr;
    const int* ip = nullptr;
    u8* mp = nullptr;

    // weight conversion (10 blocks x {plain, transposed})
    const float* wsrc[10] = { enc_e_W2, enc_n_W2, pe_W1, pe_W1 + LL, pe_W1 + 2 * LL,
                              pe_W2, pn_W1, pn_W1 + LL, pn_W2, de_W1 };
    for (int i = 0; i < 10; ++i)
        wcvt_kernel<<<gW, blk, 0, stream>>>(wsrc[i], WP(i), WT(i));

    // ================= FORWARD =================
    enc_h1_kernel<<<E_ROWS * 128 / 256, blk, 0, stream>>>(state, enc_e_W1, enc_e_b1, h1eb, menc_e);
    bgemm<false,false,true,false,false,true,false><<<gE, blk, 0, stream>>>(h1eb, WT(0), eh, up, fp, enc_e_b2, fp, fp, ip, ip, mp);
    ln_fwd_kernel<<<E_ROWS, blk, 0, stream>>>(eh, eh0b, ehb, rstd_e);
    enc_h1_kernel<<<N_ROWS * 128 / 256, blk, 0, stream>>>(state + E_ROWS, enc_n_W1, enc_n_b1, h1nb, menc_n);
    bgemm<false,false,true,false,false,true,false><<<gN, blk, 0, stream>>>(h1nb, WT(1), nh, up, fp, enc_n_b2, fp, fp, ip, ip, mp);
    ln_fwd_kernel<<<N_ROWS, blk, 0, stream>>>(nh, nh0b, nhb, rstd_n);

    for (int k = 0; k < 5; ++k) {
        bgemm<false,false,false,false,false,true,false><<<gN, blk, 0, stream>>>(nhb, WT(3), G1, up, fp, fp, fp, fp, ip, ip, mp);
        bgemm<false,false,false,false,false,true,false><<<gN, blk, 0, stream>>>(nhb, WT(4), G2, up, fp, fp, fp, fp, ip, ip, mp);
        bgemm<false,true,true,true,false,false,true><<<gE, blk, 0, stream>>>(ehb, WT(2), nullptr, h1eb, fp, pe_b1, G1, G2, senders, receivers, mpe + (size_t)k * EL);
        bgemm<true,false,true,false,false,true,true><<<gE, blk, 0, stream>>>(h1eb, WT(5), eh, ehb, eh, pe_b2, fp, fp, ip, ip, mp);
        hipMemsetAsync(agg, 0, NL * 4, stream);
        scatter_add_kernel<<<E_ROWS * 512 / 256, blk, 0, stream>>>(eh, receivers, agg);
        cvt_f2b_kernel<<<NL / 1024, blk, 0, stream>>>(agg, cvtb);
        bgemm<false,false,false,false,false,true,false><<<gN, blk, 0, stream>>>(nhb, WT(6), G1, up, fp, fp, fp, fp, ip, ip, mp);
        bgemm<true,false,true,true,false,false,true><<<gN, blk, 0, stream>>>(cvtb, WT(7), nullptr, h1nb, G1, pn_b1, fp, fp, ip, ip, mpn + (size_t)k * NL);
        bgemm<true,false,true,false,false,true,true><<<gN, blk, 0, stream>>>(h1nb, WT(8), nh, nhb, nh, pn_b2, fp, fp, ip, ip, mp);
    }

    // decoder layer-1: mask only
    bgemm<false,false,true,true,false,false,false><<<gE, blk, 0, stream>>>(ehb, WT(9), nullptr, up, fp, de_b1, fp, fp, ip, ip, mdec);

    // ================= BACKWARD =================
    dec_dh1_kernel<<<E_ROWS * 128 / 256, blk, 0, stream>>>(mdec, de_W2, h1eb);
    bgemm<false,false,false,false,false,true,true><<<gE, blk, 0, stream>>>(h1eb, WP(9), eh, ehb, fp, fp, fp, fp, ip, ip, mp);
    hipMemsetAsync(nh, 0, NL * 4, stream);
    hipMemsetAsync(nhb, 0, NL * 2, stream);

    for (int k = 4; k >= 0; --k) {
        bgemm<false,false,false,false,true,false,true><<<gN, blk, 0, stream>>>(nhb, WP(8), nullptr, h1nb, fp, fp, fp, fp, ip, ip, mpn + (size_t)k * NL);
        bgemm<true,false,false,false,false,true,false><<<gN, blk, 0, stream>>>(h1nb, WP(6), nh, up, nh, fp, fp, fp, ip, ip, mp);
        bgemm<false,false,false,false,false,true,false><<<gN, blk, 0, stream>>>(h1nb, WP(7), G1, up, fp, fp, fp, fp, ip, ip, mp);
        gather_add_kernel<<<E_ROWS * 128 / 256, blk, 0, stream>>>(eh, ehb, G1, receivers);
        bgemm<false,false,false,false,true,false,true><<<gE, blk, 0, stream>>>(ehb, WP(5), nullptr, h1eb, fp, fp, fp, fp, ip, ip, mpe + (size_t)k * EL);
        bgemm<true,false,false,false,false,true,true><<<gE, blk, 0, stream>>>(h1eb, WP(2), eh, ehb, eh, fp, fp, fp, ip, ip, mp);
        hipMemsetAsync(G2, 0, NL * 4, stream);
        hipMemsetAsync(agg, 0, NL * 4, stream);
        scatter_add_bf_kernel<<<E_ROWS * 512 / 256, blk, 0, stream>>>(h1eb, senders, G2);
        scatter_add_bf_kernel<<<E_ROWS * 512 / 256, blk, 0, stream>>>(h1eb, receivers, agg);
        cvt_f2b_kernel<<<NL / 1024, blk, 0, stream>>>(G2, cvtb);
        bgemm<true,false,false,false,false,true,false><<<gN, blk, 0, stream>>>(cvtb, WP(3), nh, up, nh, fp, fp, fp, ip, ip, mp);
        cvt_f2b_kernel<<<NL / 1024, blk, 0, stream>>>(agg, cvtb);
        bgemm<true,false,false,false,false,true,true><<<gN, blk, 0, stream>>>(cvtb, WP(4), nh, nhb, nh, fp, fp, fp, ip, ip, mp);
    }

    // encoder backward + integrator
    ln_bwd_kernel<<<E_ROWS, blk, 0, stream>>>(eh, eh0b, rstd_e, ehb);
    bgemm<false,false,false,false,true,false,true><<<gE, blk, 0, stream>>>(ehb, WP(0), nullptr, h1eb, fp, fp, fp, fp, ip, ip, menc_e);
    rowdot_out_kernel<<<E_ROWS, blk, 0, stream>>>(h1eb, enc_e_W1, state, out);
    ln_bwd_kernel<<<N_ROWS, blk, 0, stream>>>(nh, nh0b, rstd_n, nhb);
    bgemm<false,false,false,false,true,false,true><<<gN, blk, 0, stream>>>(nhb, WP(1), nullptr, h1nb, fp, fp, fp, fp, ip, ip, menc_n);
    rowdot_out_kernel<<<N_ROWS, blk, 0, stream>>>(h1nb, enc_n_W1, state + E_ROWS, out + E_ROWS);
}

// Round 3
// 1478.193 us; speedup vs baseline: 3.6877x; 1.3326x over previous
//
#include <hip/hip_runtime.h>

// Hamiltonian GNN fwd+grad, out = state - DT*dH.
// Round 3: CSR segment-sums (no memsets/atom['scatter), fused concat-GEMMs,
// single weight-convert dispatch, k=4 bwd shortcut. bf16 MFMA core kept.

#define E_ROWS 16384
#define N_ROWS 4096
#define DT_F   0.01f

typedef unsigned char u8;
typedef unsigned short u16;
typedef __attribute__((ext_vector_type(8))) short short8v;
typedef __attribute__((ext_vector_type(4))) float f32x4;

__device__ __forceinline__ u16 f2b(float f) {
    union { float f; unsigned u; } v; v.f = f;
    unsigned r = v.u + 0x7FFF + ((v.u >> 16) & 1);
    return (u16)(r >> 16);
}
__device__ __forceinline__ float b2f(u16 u) {
    union { unsigned u; float f; } v; v.u = ((unsigned)u) << 16;
    return v.f;
}

// ---------------------------------------------------------------------------
// bf16 MFMA GEMM: C[M,N] = epi(A[M,KTOT] @ Bt^T), Bt[n][k] row-major (LDB=KTOT).
// 128x128 tile, BK=32, 4 waves. LDC = C/Cin row stride. Mask buffers always
// stride 512 (only used when LDC==512).
// DUALOUT: blocks with colBase<512 -> C (+Cin); colBase>=512 -> C2 fresh,
// col-512, stride 512.
// ---------------------------------------------------------------------------
template<int KTOT, int LDA, int LDC, bool ADD_C, bool GATHER2, bool BIAS,
         bool RELU_MASK, bool APPLY_MASK, bool WF32, bool WBF16, bool DUALOUT>
__global__ __launch_bounds__(256)
void bgemm(const u16* __restrict__ A, const u16* __restrict__ Bt,
           float* __restrict__ C, u16* __restrict__ Cb,
           const float* __restrict__ Cin, const float* __restrict__ bias,
           const float* __restrict__ G12v,
           const int* __restrict__ sidx, const int* __restrict__ ridx,
           u8* __restrict__ maskw, float* __restrict__ C2)
{
    __shared__ u16 Al[4096];   // [128][32] bf16
    __shared__ u16 Bl[4096];
    const int tid = threadIdx.x;
    const int lane = tid & 63;
    const int wv = tid >> 6;
    const int wr = wv >> 1, wc = wv & 1;
    const int rowBase = blockIdx.y << 7;
    const int colBase = blockIdx.x << 7;

    const int srow = tid >> 2;
    const int kel = (tid & 3) << 3;
    const u16* Ag = A + (size_t)(rowBase + srow) * LDA + kel;
    const u16* Bg = Bt + (size_t)(colBase + srow) * KTOT + kel;
    u16* Ad = Al + (wv << 9);
    u16* Bd = Bl + (wv << 9);

    f32x4 acc[4][4];
#pragma unroll
    for (int i = 0; i < 4; ++i)
#pragma unroll
        for (int j = 0; j < 4; ++j)
            acc[i][j] = (f32x4){0.f, 0.f, 0.f, 0.f};

    const int arow = (wr << 6) + (lane & 15);
    const int brow = (wc << 6) + (lane & 15);
    const int koff = (lane >> 4) << 3;

    for (int kb = 0; kb < KTOT; kb += 32) {
        __builtin_amdgcn_global_load_lds((const __attribute__((address_space(1))) void*)(Ag + kb),
                                         (__attribute__((address_space(3))) void*)Ad, 16, 0, 0);
        __builtin_amdgcn_global_load_lds((const __attribute__((address_space(1))) void*)(Ag + kb + (size_t)64 * LDA),
                                         (__attribute__((address_space(3))) void*)(Ad + 2048), 16, 0, 0);
        __builtin_amdgcn_global_load_lds((const __attribute__((address_space(1))) void*)(Bg + kb),
                                         (__attribute__((address_space(3))) void*)Bd, 16, 0, 0);
        __builtin_amdgcn_global_load_lds((const __attribute__((address_space(1))) void*)(Bg + kb + (size_t)64 * KTOT),
                                         (__attribute__((address_space(3))) void*)(Bd + 2048), 16, 0, 0);
        __syncthreads();
        short8v af[4], bf[4];
#pragma unroll
        for (int i = 0; i < 4; ++i)
            af[i] = *(const short8v*)&Al[((arow + (i << 4)) << 5) + koff];
#pragma unroll
        for (int j = 0; j < 4; ++j)
            bf[j] = *(const short8v*)&Bl[((brow + (j << 4)) << 5) + koff];
#pragma unroll
        for (int i = 0; i < 4; ++i)
#pragma unroll
            for (int j = 0; j < 4; ++j)
                acc[i][j] = __builtin_amdgcn_mfma_f32_16x16x32_bf16(af[i], bf[j], acc[i][j], 0, 0, 0);
        __syncthreads();
    }

    const int colB = colBase + (wc << 6) + (lane & 15);
    const int rowB = rowBase + (wr << 6) + ((lane >> 4) << 2);
    float bcol[4];
    if (BIAS) {
#pragma unroll
        for (int j = 0; j < 4; ++j) bcol[j] = bias[colB + (j << 4)];
    }
    const bool upper = DUALOUT && (colBase >= 512);
#pragma unroll
    for (int i = 0; i < 4; ++i) {
#pragma unroll
        for (int r = 0; r < 4; ++r) {
            const int row = rowB + (i << 4) + r;
            int si = 0, ri = 0;
            if (GATHER2) { si = sidx[row]; ri = ridx[row]; }
#pragma unroll
            for (int j = 0; j < 4; ++j) {
                const int col = colB + (j << 4);
                float v = acc[i][j][r];
                if (DUALOUT) {
                    if (upper) {
                        C2[(size_t)row * 512 + (col - 512)] = v;
                    } else {
                        if (ADD_C) v += Cin[(size_t)row * 512 + col];
                        C[(size_t)row * 512 + col] = v;
                    }
                    continue;
                }
                if (GATHER2) v += G12v[(size_t)si * 1024 + col] + G12v[(size_t)ri * 1024 + 512 + col];
                if (ADD_C) v += Cin[(size_t)row * LDC + col];
                if (BIAS) v += bcol[j];
                const size_t o = (size_t)row * LDC + col;
                if (RELU_MASK) {
                    const u8 m = v > 0.f;
                    maskw[o] = m;
                    v = m ? v : 0.f;
                }
                if (APPLY_MASK) {
                    if (!maskw[o]) v = 0.f;
                }
                if (WF32) C[o] = v;
                if (WBF16) Cb[o] = f2b(v);
            }
        }
    }
}

// ---------------------------------------------------------------------------
// Weight convert, all 10 blocks in one dispatch. Per i: plain Wp[r*ldP+c],
// transposed Wt[c*ldT+r]. grid (8,8,10).
// ---------------------------------------------------------------------------
struct WArgs {
    const float* src[10];
    u16* dstP[10];
    u16* dstT[10];
    int ldP[10], ldT[10];
};

__global__ void wcvt_kernel(WArgs a)
{
    const int i = blockIdx.z;
    const float* W = a.src[i];
    u16* P = a.dstP[i]; const int lp = a.ldP[i];
    u16* T = a.dstT[i]; const int lt = a.ldT[i];
    __shared__ u16 t[64][66];
    const int rb = blockIdx.y << 6, cb = blockIdx.x << 6;
    const int tr = threadIdx.x >> 4;
    const int tc = (threadIdx.x & 15) << 2;
#pragma unroll
    for (int rr = 0; rr < 4; ++rr) {
        const int r = tr + (rr << 4);
        const float4 v = *(const float4*)&W[(size_t)(rb + r) * 512 + cb + tc];
        ushort4 u; u.x = f2b(v.x); u.y = f2b(v.y); u.z = f2b(v.z); u.w = f2b(v.w);
        *(ushort4*)&P[(size_t)(rb + r) * lp + cb + tc] = u;
        t[r][tc] = u.x; t[r][tc + 1] = u.y; t[r][tc + 2] = u.z; t[r][tc + 3] = u.w;
    }
    __syncthreads();
#pragma unroll
    for (int rr = 0; rr < 4; ++rr) {
        const int n = tr + (rr << 4);
        ushort4 u;
        u.x = t[tc][n]; u.y = t[tc + 1][n]; u.z = t[tc + 2][n]; u.w = t[tc + 3][n];
        *(ushort4*)&T[(size_t)(cb + n) * lt + rb + tc] = u;
    }
}

// ---------------------------------------------------------------------------
// CSR build for one index array: starts[4097], eids[16384] (sorted per node
// for determinism). One block, 1024 threads.
// ---------------------------------------------------------------------------
__global__ __launch_bounds__(1024) void csr_build_kernel(const int* __restrict__ idx,
                                                         int* __restrict__ starts,
                                                         int* __restrict__ eids)
{
    __shared__ int hist[4096];
    __shared__ int scanbuf[1024];
    const int t = threadIdx.x;
    for (int i = t; i < 4096; i += 1024) hist[i] = 0;
    __syncthreads();
    for (int e = t; e < 16384; e += 1024) atomicAdd(&hist[idx[e]], 1);
    __syncthreads();
    const int base = t << 2;
    const int l0 = hist[base], l1 = hist[base + 1], l2 = hist[base + 2], l3 = hist[base + 3];
    const int lsum = l0 + l1 + l2 + l3;
    scanbuf[t] = lsum;
    __syncthreads();
    for (int ofs = 1; ofs < 1024; ofs <<= 1) {
        const int v = scanbuf[t];
        const int u = (t >= ofs) ? scanbuf[t - ofs] : 0;
        __syncthreads();
        scanbuf[t] = v + u;
        __syncthreads();
    }
    const int excl = scanbuf[t] - lsum;
    const int p0 = excl, p1 = p0 + l0, p2 = p1 + l1, p3 = p2 + l2;
    starts[base] = p0; starts[base + 1] = p1; starts[base + 2] = p2; starts[base + 3] = p3;
    if (t == 0) starts[4096] = 16384;
    __syncthreads();
    hist[base] = p0; hist[base + 1] = p1; hist[base + 2] = p2; hist[base + 3] = p3;
    __syncthreads();
    for (int e = t; e < 16384; e += 1024) {
        const int pos = atomicAdd(&hist[idx[e]], 1);
        eids[pos] = e;
    }
    __syncthreads();
    // deterministic order: insertion-sort each segment (avg deg 4)
    for (int n = t; n < 4096; n += 1024) {
        const int s0 = starts[n], s1 = hist[n];
        for (int i = s0 + 1; i < s1; ++i) {
            const int v = eids[i];
            int j = i - 1;
            while (j >= s0 && eids[j] > v) { eids[j + 1] = eids[j]; --j; }
            eids[j + 1] = v;
        }
    }
}

// fwd: nagg[n][0:512] = nhb[n], nagg[n][512:1024] = bf16(segsum(eh fp32, recv)).
__global__ void seg_agg_fwd_kernel(const float* __restrict__ eh, const int* __restrict__ starts,
                                   const int* __restrict__ eids, const u16* __restrict__ nhb,
                                   u16* __restrict__ nagg)
{
    const int n = blockIdx.x, c = threadIdx.x;
    const int s0 = starts[n], s1 = starts[n + 1];
    float a0 = 0.f, a1 = 0.f;
    for (int i = s0; i < s1; ++i) {
        const float* p = eh + (size_t)eids[i] * 512;
        a0 += p[c]; a1 += p[c + 256];
    }
    u16* d = nagg + (size_t)n * 1024;
    const u16* s = nhb + (size_t)n * 512;
    d[c] = s[c]; d[c + 256] = s[c + 256];
    d[512 + c] = f2b(a0); d[768 + c] = f2b(a1);
}

// bwd: SR[n][0:512] = segsum(dh1e bf16, senders), [512:1024] = segsum(.., recv).
__global__ void seg_sr_bwd_kernel(const u16* __restrict__ dh1e,
                                  const int* __restrict__ sst, const int* __restrict__ seid,
                                  const int* __restrict__ rst, const int* __restrict__ reid,
                                  u16* __restrict__ SR)
{
    const int n = blockIdx.x, c = threadIdx.x;
    float a0 = 0.f, a1 = 0.f, b0 = 0.f, b1 = 0.f;
    for (int i = sst[n]; i < sst[n + 1]; ++i) {
        const u16* p = dh1e + (size_t)seid[i] * 512;
        a0 += b2f(p[c]); a1 += b2f(p[c + 256]);
    }
    for (int i = rst[n]; i < rst[n + 1]; ++i) {
        const u16* p = dh1e + (size_t)reid[i] * 512;
        b0 += b2f(p[c]); b1 += b2f(p[c + 256]);
    }
    u16* d = SR + (size_t)n * 1024;
    d[c] = f2b(a0); d[c + 256] = f2b(a1);
    d[512 + c] = f2b(b0); d[768 + c] = f2b(b1);
}

// Encoder layer-1: h1 = relu(x*W1+b1) -> bf16 + mask.
__global__ void enc_h1_kernel(const float* __restrict__ x, const float* __restrict__ W1,
                              const float* __restrict__ b1, u16* __restrict__ h1b,
                              u8* __restrict__ mask)
{
    const int idx = blockIdx.x * 256 + threadIdx.x;
    const int row = idx >> 7;
    const int c = (idx & 127) << 2;
    const float xv = x[row];
    const float4 w = *(const float4*)&W1[c];
    const float4 b = *(const float4*)&b1[c];
    float4 v;
    v.x = fmaf(xv, w.x, b.x); v.y = fmaf(xv, w.y, b.y);
    v.z = fmaf(xv, w.z, b.z); v.w = fmaf(xv, w.w, b.w);
    uchar4 m;
    m.x = v.x > 0.f; m.y = v.y > 0.f; m.z = v.z > 0.f; m.w = v.w > 0.f;
    v.x = m.x ? v.x : 0.f; v.y = m.y ? v.y : 0.f;
    v.z = m.z ? v.z : 0.f; v.w = m.w ? v.w : 0.f;
    const size_t o = (size_t)row * 512 + c;
    ushort4 u; u.x = f2b(v.x); u.y = f2b(v.y); u.z = f2b(v.z); u.w = f2b(v.w);
    *(ushort4*)&h1b[o] = u;
    *(uchar4*)&mask[o] = m;
}

__global__ void ln_fwd_kernel(float* __restrict__ x, u16* __restrict__ xhat_b,
                              u16* __restrict__ xb, float* __restrict__ rstd_save)
{
    const int row = blockIdx.x, tid = threadIdx.x;
    float* p = x + (size_t)row * 512;
    const float a = p[tid], b = p[tid + 256];
    __shared__ float s1[256], s2[256];
    s1[tid] = a + b; s2[tid] = a * a + b * b;
    __syncthreads();
    for (int d = 128; d > 0; d >>= 1) {
        if (tid < d) { s1[tid] += s1[tid + d]; s2[tid] += s2[tid + d]; }
        __syncthreads();
    }
    const float mean = s1[0] * (1.f / 512.f);
    const float var = s2[0] * (1.f / 512.f) - mean * mean;
    const float r = rsqrtf(var + 1e-6f);
    const float ya = (a - mean) * r, yb = (b - mean) * r;
    p[tid] = ya; p[tid + 256] = yb;
    const size_t o = (size_t)row * 512 + tid;
    xhat_b[o] = f2b(ya); xhat_b[o + 256] = f2b(yb);
    xb[o] = f2b(ya); xb[o + 256] = f2b(yb);
    if (tid == 0) rstd_save[row] = r;
}

__global__ void ln_bwd_kernel(float* __restrict__ d, const u16* __restrict__ xhat_b,
                              const float* __restrict__ rstd, u16* __restrict__ db)
{
    const int row = blockIdx.x, tid = threadIdx.x;
    float* p = d + (size_t)row * 512;
    const u16* xh = xhat_b + (size_t)row * 512;
    const float da = p[tid], dbv = p[tid + 256];
    const float xa = b2f(xh[tid]), xbv = b2f(xh[tid + 256]);
    __shared__ float s1[256], s2[256];
    s1[tid] = da + dbv; s2[tid] = da * xa + dbv * xbv;
    __syncthreads();
    for (int dd = 128; dd > 0; dd >>= 1) {
        if (tid < dd) { s1[tid] += s1[tid + dd]; s2[tid] += s2[tid + dd]; }
        __syncthreads();
    }
    const float m1 = s1[0] * (1.f / 512.f);
    const float m2 = s2[0] * (1.f / 512.f);
    const float r = rstd[row];
    const float oa = r * (da - m1 - xa * m2);
    const float ob = r * (dbv - m1 - xbv * m2);
    p[tid] = oa; p[tid + 256] = ob;
    db[(size_t)row * 512 + tid] = f2b(oa);
    db[(size_t)row * 512 + tid + 256] = f2b(ob);
}

// d_eh[row] += d_agg[receivers[row]] ; refresh bf16 copy.
__global__ void gather_add_kernel(float* __restrict__ dst, u16* __restrict__ dstb,
                                  const float* __restrict__ src, const int* __restrict__ idx)
{
    const int t = blockIdx.x * 256 + threadIdx.x;
    const int row = t >> 7;
    const int c = (t & 127) << 2;
    const size_t o = (size_t)row * 512 + c;
    float4 a = *(const float4*)&dst[o];
    const float4 g = *(const float4*)&src[(size_t)idx[row] * 512 + c];
    a.x += g.x; a.y += g.y; a.z += g.z; a.w += g.w;
    *(float4*)&dst[o] = a;
    ushort4 u; u.x = f2b(a.x); u.y = f2b(a.y); u.z = f2b(a.z); u.w = f2b(a.w);
    *(ushort4*)&dstb[o] = u;
}

// dh1_dec = mask ? W2 : 0 (bf16)
__global__ void dec_dh1_kernel(const u8* __restrict__ mask, const float* __restrict__ W2,
                               u16* __restrict__ dh1b)
{
    const int t = blockIdx.x * 256 + threadIdx.x;
    const int row = t >> 7;
    const int c = (t & 127) << 2;
    const size_t o = (size_t)row * 512 + c;
    const uchar4 m = *(const uchar4*)&mask[o];
    const float4 w = *(const float4*)&W2[c];
    ushort4 u;
    u.x = m.x ? f2b(w.x) : 0; u.y = m.y ? f2b(w.y) : 0;
    u.z = m.z ? f2b(w.z) : 0; u.w = m.w ? f2b(w.w) : 0;
    *(ushort4*)&dh1b[o] = u;
}

__global__ void rowdot_out_kernel(const u16* __restrict__ dh1b, const float* __restrict__ w,
                                  const float* __restrict__ xin, float* __restrict__ out)
{
    const int row = blockIdx.x, tid = threadIdx.x;
    const u16* p = dh1b + (size_t)row * 512;
    float s = b2f(p[tid]) * w[tid] + b2f(p[tid + 256]) * w[tid + 256];
    __shared__ float sh[256];
    sh[tid] = s;
    __syncthreads();
    for (int d = 128; d > 0; d >>= 1) {
        if (tid < d) sh[tid] += sh[tid + d];
        __syncthreads();
    }
    if (tid == 0) out[row] = xin[row] - DT_F * sh[0];
}

// ---------------------------------------------------------------------------
extern "C" void kernel_launch(void* const* d_in, const int* in_sizes, int n_in,
                              void* d_out, int out_size, void* d_ws, size_t ws_size,
                              hipStream_t stream)
{
    (void)in_sizes; (void)n_in; (void)out_size; (void)ws_size;
    const float* state     = (const float*)d_in[0];
    const int*   senders   = (const int*)d_in[1];
    const int*   receivers = (const int*)d_in[2];
    const float* enc_e_W1 = (const float*)d_in[3];
    const float* enc_e_b1 = (const float*)d_in[4];
    const float* enc_e_W2 = (const float*)d_in[5];
    const float* enc_e_b2 = (const float*)d_in[6];
    const float* enc_n_W1 = (const float*)d_in[7];
    const float* enc_n_b1 = (const float*)d_in[8];
    const float* enc_n_W2 = (const float*)d_in[9];
    const float* enc_n_b2 = (const float*)d_in[10];
    const float* pe_W1 = (const float*)d_in[11];
    const float* pe_b1 = (const float*)d_in[12];
    const float* pe_W2 = (const float*)d_in[13];
    const float* pe_b2 = (const float*)d_in[14];
    const float* pn_W1 = (const float*)d_in[15];
    const float* pn_b1 = (const float*)d_in[16];
    const float* pn_W2 = (const float*)d_in[17];
    const float* pn_b2 = (const float*)d_in[18];
    const float* de_W1 = (const float*)d_in[19];
    const float* de_b1 = (const float*)d_in[20];
    const float* de_W2 = (const float*)d_in[21];
    float* out = (float*)d_out;

    const size_t EL = (size_t)E_ROWS * 512, NL = (size_t)N_ROWS * 512;
    const size_t LL = 512 * 512;
    char* w = (char*)d_ws;
    size_t off = 0;
    auto carve = [&](size_t bytes) -> char* {
        char* p = w + off;
        off += (bytes + 255) & ~(size_t)255;
        return p;
    };
    u16* wb = (u16*)carve(20 * LL * 2);
    // LL-unit layout: WT0 WT1 WT2 WT3 WT4 WT5 WT8 WT9 WP0 WP1 WP2 WP5 WP8 WP9
    //                 WT67(2) WP34c(2) WP67(2)
    u16* WT0 = wb;           u16* WT1 = wb + LL;      u16* WT2 = wb + 2 * LL;
    u16* WT34 = wb + 3 * LL; /* WT3|WT4 adjacent */   u16* WT5 = wb + 5 * LL;
    u16* WT8 = wb + 6 * LL;  u16* WT9 = wb + 7 * LL;
    u16* WP0 = wb + 8 * LL;  u16* WP1 = wb + 9 * LL;  u16* WP2 = wb + 10 * LL;
    u16* WP5 = wb + 11 * LL; u16* WP8 = wb + 12 * LL; u16* WP9 = wb + 13 * LL;
    u16* WT67 = wb + 14 * LL;   // [512][1024]
    u16* WP34c = wb + 16 * LL;  // [512][1024]
    u16* WP67 = wb + 18 * LL;   // [1024][512] (WP6 rows then WP7 rows)

    float* eh  = (float*)carve(EL * 4);
    float* nh  = (float*)carve(NL * 4);
    float* G12 = (float*)carve(NL * 2 * 4);   // [4096][1024] fp32
    float* G1  = (float*)carve(NL * 4);       // bwd d_agg
    u16* nsr   = (u16*)carve(NL * 2 * 2);     // fwd nagg / bwd SR [4096][1024]
    u16* eh0b = (u16*)carve(EL * 2);
    u16* nh0b = (u16*)carve(NL * 2);
    u16* ehb  = (u16*)carve(EL * 2);
    u16* h1eb = (u16*)carve(EL * 2);
    u16* nhb  = (u16*)carve(NL * 2);
    u16* h1nb = (u16*)carve(NL * 2);
    float* rstd_e = (float*)carve(E_ROWS * 4);
    float* rstd_n = (float*)carve(N_ROWS * 4);
    u8* menc_e = (u8*)carve(EL);
    u8* menc_n = (u8*)carve(NL);
    u8* mpe    = (u8*)carve(5 * EL);
    u8* mpn    = (u8*)carve(5 * NL);
    u8* mdec   = (u8*)carve(EL);
    int* rst  = (int*)carve(4097 * 4);
    int* reid = (int*)carve(16384 * 4);
    int* sst  = (int*)carve(4097 * 4);
    int* seid = (int*)carve(16384 * 4);

    const dim3 blk(256);
    const dim3 gE(4, E_ROWS / 128), gN(4, N_ROWS / 128);
    const dim3 gN1024(8, N_ROWS / 128);
    const float* fp = nullptr;
    u16* up = nullptr;
    const int* ip = nullptr;
    u8* mp = nullptr;
    float* f2p = nullptr;

    // ---- weight conversion: one dispatch ----
    WArgs wa;
    const float* wsrc[10] = { enc_e_W2, enc_n_W2, pe_W1, pe_W1 + LL, pe_W1 + 2 * LL,
                              pe_W2, pn_W1, pn_W1 + LL, pn_W2, de_W1 };
    u16* dstP[10] = { WP0, WP1, WP2, WP34c, WP34c + 512, WP5, WP67, WP67 + LL, WP8, WP9 };
    int  ldP [10] = { 512, 512, 512, 1024,  1024,        512, 512,  512,       512, 512 };
    u16* dstT[10] = { WT0, WT1, WT2, WT34, WT34 + LL, WT5, WT67, WT67 + 512, WT8, WT9 };
    int  ldT [10] = { 512, 512, 512, 512,  512,       512, 1024, 1024,       512, 512 };
    for (int i = 0; i < 10; ++i) {
        wa.src[i] = wsrc[i]; wa.dstP[i] = dstP[i]; wa.dstT[i] = dstT[i];
        wa.ldP[i] = ldP[i]; wa.ldT[i] = ldT[i];
    }
    wcvt_kernel<<<dim3(8, 8, 10), blk, 0, stream>>>(wa);

    // ---- CSR build (receivers, senders) ----
    csr_build_kernel<<<1, 1024, 0, stream>>>(receivers, rst, reid);
    csr_build_kernel<<<1, 1024, 0, stream>>>(senders, sst, seid);

    // ================= FORWARD =================
    enc_h1_kernel<<<E_ROWS * 128 / 256, blk, 0, stream>>>(state, enc_e_W1, enc_e_b1, h1eb, menc_e);
    bgemm<512,512,512,false,false,true,false,false,true,false,false><<<gE, blk, 0, stream>>>(h1eb, WT0, eh, up, fp, enc_e_b2, fp, ip, ip, mp, f2p);
    ln_fwd_kernel<<<E_ROWS, blk, 0, stream>>>(eh, eh0b, ehb, rstd_e);
    enc_h1_kernel<<<N_ROWS * 128 / 256, blk, 0, stream>>>(state + E_ROWS, enc_n_W1, enc_n_b1, h1nb, menc_n);
    bgemm<512,512,512,false,false,true,false,false,true,false,false><<<gN, blk, 0, stream>>>(h1nb, WT1, nh, up, fp, enc_n_b2, fp, ip, ip, mp, f2p);
    ln_fwd_kernel<<<N_ROWS, blk, 0, stream>>>(nh, nh0b, nhb, rstd_n);

    for (int k = 0; k < 5; ++k) {
        // G12[m][0:512] = nh@W1b ; [512:1024] = nh@W1c  (N=1024 fused)
        bgemm<512,512,1024,false,false,false,false,false,true,false,false><<<gN1024, blk, 0, stream>>>(nhb, WT34, G12, up, fp, fp, fp, ip, ip, mp, f2p);
        // h1e = relu(eh@W1a + G12[s][:512] + G12[r][512:] + b1), mask
        bgemm<512,512,512,false,true,true,true,false,false,true,false><<<gE, blk, 0, stream>>>(ehb, WT2, nullptr, h1eb, fp, pe_b1, G12, senders, receivers, mpe + (size_t)k * EL, f2p);
        // eh += h1e@W2 + b2
        bgemm<512,512,512,true,false,true,false,false,true,true,false><<<gE, blk, 0, stream>>>(h1eb, WT5, eh, ehb, eh, pe_b2, fp, ip, ip, mp, f2p);
        // nagg = [nhb | bf16(segsum(eh, recv))]
        seg_agg_fwd_kernel<<<N_ROWS, blk, 0, stream>>>(eh, rst, reid, nhb, nsr);
        // h1n = relu(nagg@[W1na;W1nb] + b1), K=1024, mask
        bgemm<1024,1024,512,false,false,true,true,false,false,true,false><<<gN, blk, 0, stream>>>(nsr, WT67, nullptr, h1nb, fp, pn_b1, fp, ip, ip, mpn + (size_t)k * NL, f2p);
        // nh += h1n@W2 + b2
        bgemm<512,512,512,true,false,true,false,false,true,true,false><<<gN, blk, 0, stream>>>(h1nb, WT8, nh, nhb, nh, pn_b2, fp, ip, ip, mp, f2p);
    }

    // decoder layer-1: mask only
    bgemm<512,512,512,false,false,true,true,false,false,false,false><<<gE, blk, 0, stream>>>(ehb, WT9, nullptr, up, fp, de_b1, fp, ip, ip, mdec, f2p);

    // ================= BACKWARD =================
    dec_dh1_kernel<<<E_ROWS * 128 / 256, blk, 0, stream>>>(mdec, de_W2, h1eb);
    bgemm<512,512,512,false,false,false,false,false,true,true,false><<<gE, blk, 0, stream>>>(h1eb, WP9, eh, ehb, fp, fp, fp, ip, ip, mp, f2p);

    for (int k = 4; k >= 0; --k) {
        if (k < 4) {
            // dh1n = (d_nh@Wn2^T)*mask
            bgemm<512,512,512,false,false,false,false,true,false,true,false><<<gN, blk, 0, stream>>>(nhb, WP8, nullptr, h1nb, fp, fp, fp, ip, ip, mpn + (size_t)k * NL, f2p);
            // d_nh += dh1n@Wn1a^T (lower) ; d_agg = dh1n@Wn1b^T (upper)  [DUALOUT]
            bgemm<512,512,512,true,false,false,false,false,true,false,true><<<gN1024, blk, 0, stream>>>(h1nb, WP67, nh, up, nh, fp, fp, ip, ip, mp, G1);
            // d_eh += d_agg[receivers]
            gather_add_kernel<<<E_ROWS * 128 / 256, blk, 0, stream>>>(eh, ehb, G1, receivers);
        }
        // dh1e = (d_eh@We2^T)*mask
        bgemm<512,512,512,false,false,false,false,true,false,true,false><<<gE, blk, 0, stream>>>(ehb, WP5, nullptr, h1eb, fp, fp, fp, ip, ip, mpe + (size_t)k * EL, f2p);
        // d_eh += dh1e@We1a^T
        bgemm<512,512,512,true,false,false,false,false,true,true,false><<<gE, blk, 0, stream>>>(h1eb, WP2, eh, ehb, eh, fp, fp, ip, ip, mp, f2p);
        // SR = [segsum(dh1e,send) | segsum(dh1e,recv)] bf16
        seg_sr_bwd_kernel<<<N_ROWS, blk, 0, stream>>>(h1eb, sst, seid, rst, reid, nsr);
        // d_nh (+)= SR @ [We1b;We1c]^T, K=1024
        if (k == 4)
            bgemm<1024,1024,512,false,false,false,false,false,true,true,false><<<gN, blk, 0, stream>>>(nsr, WP34c, nh, nhb, fp, fp, fp, ip, ip, mp, f2p);
        else
            bgemm<1024,1024,512,true,false,false,false,false,true,true,false><<<gN, blk, 0, stream>>>(nsr, WP34c, nh, nhb, nh, fp, fp, ip, ip, mp, f2p);
    }

    // encoder backward + integrator
    ln_bwd_kernel<<<E_ROWS, blk, 0, stream>>>(eh, eh0b, rstd_e, ehb);
    bgemm<512,512,512,false,false,false,false,true,false,true,false><<<gE, blk, 0, stream>>>(ehb, WP0, nullptr, h1eb, fp, fp, fp, ip, ip, menc_e, f2p);
    rowdot_out_kernel<<<E_ROWS, blk, 0, stream>>>(h1eb, enc_e_W1, state, out);
    ln_bwd_kernel<<<N_ROWS, blk, 0, stream>>>(nh, nh0b, rstd_n, nhb);
    bgemm<512,512,512,false,false,false,false,true,false,true,false><<<gN, blk, 0, stream>>>(nhb, WP1, nullptr, h1nb, fp, fp, fp, ip, ip, menc_n, f2p);
    rowdot_out_kernel<<<N_ROWS, blk, 0, stream>>>(h1nb, enc_n_W1, state + E_ROWS, out + E_ROWS);
}